// Round 1
// baseline (462.506 us; speedup 1.0000x reference)
//
#include <hip/hip_runtime.h>
#include <hip/hip_bf16.h>
#include <cstddef>

#define CH 128
#define BN_EPS 1e-5f
#define STATS_BLOCKS 1024

typedef __bf16 bf16x8 __attribute__((ext_vector_type(8)));
typedef __bf16 bf16x4 __attribute__((ext_vector_type(4)));
typedef float  f32x4  __attribute__((ext_vector_type(4)));

__device__ inline float bf2f(__bf16 b) { return (float)b; }

__device__ inline f32x4 nt_load4(const float* p) {
    return __builtin_nontemporal_load((const f32x4*)p);
}
__device__ inline void nt_store4(float* p, f32x4 v) {
    __builtin_nontemporal_store(v, (f32x4*)p);
}

// ---------------------------------------------------------------------------
// R7: launch-count collapse (20 -> 8) + stats2 fused into agg1 + nontemporal
// streaming writes. Scan becomes single-kernel via atomic block-base cursor
// (offs no longer monotonic; agg uses end = offs[node] + cnt[node]).
// ---------------------------------------------------------------------------

// ---- K1: count (atomics) + stats1 over x + wprep W1,W2 -> bf16 -------------
__global__ __launch_bounds__(256) void k1_kernel(
    const int* __restrict__ dst, int* __restrict__ cnt, int* __restrict__ slot, int E,
    const float* __restrict__ x, float* __restrict__ partials, int total4,
    const float* __restrict__ W1, const float* __restrict__ W2,
    __bf16* __restrict__ W1b, __bf16* __restrict__ W2b,
    int NB_COUNT, int NB_STATS) {
    int b = blockIdx.x;
    if (b < NB_COUNT) {
        int e = b * 256 + threadIdx.x;
        if (e < E) slot[e] = atomicAdd(&cnt[dst[e]], 1);
    } else if (b < NB_COUNT + NB_STATS) {
        // per-channel sum & sumsq -> per-block partial row (sums||sumsq)
        int sbid = b - NB_COUNT;
        int l = threadIdx.x & 31;
        int g = threadIdx.x >> 5;
        float4 s  = make_float4(0.f, 0.f, 0.f, 0.f);
        float4 s2 = make_float4(0.f, 0.f, 0.f, 0.f);
        int gid = sbid * 256 + threadIdx.x;
        int gs = NB_STATS * 256;
        const float4* in4 = (const float4*)x;

        auto accum = [&](float4 v) {
            s.x += v.x; s.y += v.y; s.z += v.z; s.w += v.w;
            s2.x += v.x * v.x; s2.y += v.y * v.y; s2.z += v.z * v.z; s2.w += v.w * v.w;
        };

        int i = gid;
        for (; i + 3 * gs < total4; i += 4 * gs) {
            float4 v0 = in4[i];
            float4 v1 = in4[i + gs];
            float4 v2 = in4[i + 2 * gs];
            float4 v3 = in4[i + 3 * gs];
            accum(v0); accum(v1); accum(v2); accum(v3);
        }
        for (; i < total4; i += gs) accum(in4[i]);

        __shared__ float4 ls[8][32], ls2[8][32];
        ls[g][l] = s; ls2[g][l] = s2;
        __syncthreads();
        if (g == 0) {
            #pragma unroll
            for (int k = 1; k < 8; ++k) {
                float4 a = ls[k][l], bb = ls2[k][l];
                s.x += a.x; s.y += a.y; s.z += a.z; s.w += a.w;
                s2.x += bb.x; s2.y += bb.y; s2.z += bb.z; s2.w += bb.w;
            }
            ((float4*)partials)[sbid * 64 + l]      = s;
            ((float4*)partials)[sbid * 64 + 32 + l] = s2;
        }
    } else {
        int i = (b - NB_COUNT - NB_STATS) * 256 + threadIdx.x;
        if (i < CH * CH) W1b[i] = (__bf16)W1[i];
        else if (i < 2 * CH * CH) W2b[i - CH * CH] = (__bf16)W2[i - CH * CH];
    }
}

// ---- reduce partial rows + BN params (8 channels per block, 16 blocks) -----
__device__ inline void reducebn_body(
    int blk, const float* __restrict__ partials, int R,
    const float* __restrict__ gamma, const float* __restrict__ beta,
    float* __restrict__ scale, float* __restrict__ shift, float inv_n) {
    __shared__ float l1[256], l2[256];
    int t = threadIdx.x;
    int cl = t & 7;
    int r0 = t >> 3;
    int c = blk * 8 + cl;
    float a1 = 0.f, a2 = 0.f;
    for (int r = r0; r < R; r += 32) {
        a1 += partials[(size_t)r * 256 + c];
        a2 += partials[(size_t)r * 256 + 128 + c];
    }
    l1[t] = a1; l2[t] = a2;
    __syncthreads();
    #pragma unroll
    for (int off = 16; off >= 1; off >>= 1) {
        if (r0 < off) {
            l1[t] += l1[t + off * 8];
            l2[t] += l2[t + off * 8];
        }
        __syncthreads();
    }
    if (t < 8) {
        float mean = l1[t] * inv_n;
        float var  = l2[t] * inv_n - mean * mean;  // biased
        float sc = gamma[c] * rsqrtf(var + BN_EPS);
        scale[c] = sc;
        shift[c] = beta[c] - mean * sc;
    }
}

// ---- K2: atomic-base scan + dinv + reduce1/bnparam1 ------------------------
__global__ __launch_bounds__(256) void k2_kernel(
    const int* __restrict__ cnt, int* __restrict__ offs, int* __restrict__ cursor,
    float* __restrict__ dinv, int n,
    const float* __restrict__ partials,
    const float* __restrict__ gamma1, const float* __restrict__ beta1,
    float* __restrict__ scale1, float* __restrict__ shift1,
    int R, int NB_SCAN, int NB_DINV) {
    int b = blockIdx.x;
    if (b < NB_SCAN) {
        __shared__ int sd[256];
        __shared__ int sbase;
        int t = threadIdx.x;
        int base = b * 1024 + t * 4;
        int v[4];
        #pragma unroll
        for (int j = 0; j < 4; ++j) v[j] = (base + j < n) ? cnt[base + j] : 0;
        int s = v[0] + v[1] + v[2] + v[3];
        sd[t] = s;
        __syncthreads();
        for (int off = 1; off < 256; off <<= 1) {
            int xv = (t >= off) ? sd[t - off] : 0;
            __syncthreads();
            sd[t] += xv;
            __syncthreads();
        }
        if (t == 255) sbase = atomicAdd(cursor, sd[255]);
        __syncthreads();
        int run = sbase + sd[t] - s;
        #pragma unroll
        for (int j = 0; j < 4; ++j) {
            if (base + j < n) offs[base + j] = run;
            run += v[j];
        }
    } else if (b < NB_SCAN + NB_DINV) {
        int ib = (b - NB_SCAN) * 1024 + threadIdx.x * 4;
        #pragma unroll
        for (int j = 0; j < 4; ++j) {
            int i = ib + j;
            if (i < n) dinv[i] = rsqrtf((float)cnt[i] + 1.0f);  // +1 self loop
        }
    } else {
        reducebn_body(b - NB_SCAN - NB_DINV, partials, R, gamma1, beta1,
                      scale1, shift1, 1.0f / (float)n);
    }
}

__global__ __launch_bounds__(256) void reducebn_kernel(
    const float* __restrict__ partials, int R,
    const float* __restrict__ gamma, const float* __restrict__ beta,
    float* __restrict__ scale, float* __restrict__ shift, int n) {
    reducebn_body(blockIdx.x, partials, R, gamma, beta, scale, shift, 1.0f / (float)n);
}

// ---- MFMA GEMM body --------------------------------------------------------
#define GROWS 64
#define LDA 136

__device__ inline void gemm_body(
    int bid, const float* __restrict__ A, const float* __restrict__ bias, int do_relu,
    const float* __restrict__ scale, const float* __restrict__ shift,
    const __bf16* __restrict__ Wb, __bf16* __restrict__ Hout, int n, int ntA) {
    __shared__ __bf16 As[GROWS][LDA];
    int tid = threadIdx.x;
    int row0 = bid * GROWS;

    #pragma unroll
    for (int p = 0; p < 8; ++p) {
        int idx = p * 256 + tid;
        int r = idx >> 5;
        int f4 = idx & 31;
        int c4 = f4 * 4;
        int row = row0 + r;
        f32x4 v = {0.f, 0.f, 0.f, 0.f};
        if (row < n) {
            const f32x4* p4 = (const f32x4*)A + ((size_t)row * 32 + f4);
            v = ntA ? __builtin_nontemporal_load(p4) : *p4;
        }
        __bf16 u[4];
        #pragma unroll
        for (int j = 0; j < 4; ++j) {
            int ch = c4 + j;
            float f = v[j];
            if (do_relu) f = fmaxf(f + bias[ch], 0.f);
            f = f * scale[ch] + shift[ch];
            u[j] = (__bf16)f;
        }
        *(bf16x4*)&As[r][c4] = *(bf16x4*)u;
    }
    __syncthreads();

    int wv = tid >> 6;
    int lane = tid & 63;
    int m = lane & 15;
    int q = lane >> 4;
    int arow = wv * 16 + m;
    f32x4 acc[8] = {};
    #pragma unroll
    for (int kc = 0; kc < CH; kc += 32) {
        bf16x8 af = *(const bf16x8*)&As[arow][kc + q * 8];
        #pragma unroll
        for (int t = 0; t < 8; ++t) {
            bf16x8 bf = *(const bf16x8*)&Wb[(size_t)(t * 16 + m) * CH + kc + q * 8];
            acc[t] = __builtin_amdgcn_mfma_f32_16x16x32_bf16(af, bf, acc[t], 0, 0, 0);
        }
    }

    #pragma unroll
    for (int t = 0; t < 8; ++t) {
        #pragma unroll
        for (int r = 0; r < 4; ++r) {
            int row = row0 + wv * 16 + q * 4 + r;
            if (row < n) Hout[(size_t)row * CH + t * 16 + m] = (__bf16)acc[t][r];
        }
    }
}

// ---- K3: fill CSR + gemm1 (independent, block-range fused) -----------------
__global__ __launch_bounds__(256) void k3_kernel(
    const int* __restrict__ src, const int* __restrict__ dst,
    const int* __restrict__ slot, const int* __restrict__ offs,
    const float* __restrict__ dinv, int2* __restrict__ csr, int E,
    const float* __restrict__ A,
    const float* __restrict__ scale, const float* __restrict__ shift,
    const __bf16* __restrict__ Wb, __bf16* __restrict__ Hout, int n,
    int NB_FILL) {
    if (blockIdx.x < NB_FILL) {
        int e = blockIdx.x * 256 + threadIdx.x;
        if (e >= E) return;
        int s = src[e], d = dst[e];
        int p = offs[d] + slot[e];
        float nrm = dinv[s] * dinv[d];
        csr[p] = make_int2(s, __float_as_int(nrm));
    } else {
        gemm_body(blockIdx.x - NB_FILL, A, nullptr, 0, scale, shift, Wb, Hout, n, 0);
    }
}

__global__ __launch_bounds__(256) void gemm_kernel(
    const float* __restrict__ A, const float* __restrict__ bias, int do_relu,
    const float* __restrict__ scale, const float* __restrict__ shift,
    const __bf16* __restrict__ Wb, __bf16* __restrict__ Hout, int n, int ntA) {
    gemm_body(blockIdx.x, A, bias, do_relu, scale, shift, Wb, Hout, n, ntA);
}

// ---------------------------------------------------------------------------
// Gather aggregation: 16 lanes/node, 8 ch/lane, 16 nodes/block.
// mode 0: writes agg_buf (nt) + fused stage-2 stats partial row per block.
// mode 1: final relu + bias + residual, nt store to out.
// ---------------------------------------------------------------------------
__global__ __launch_bounds__(256) void agg_kernel(
    const __bf16* __restrict__ h, const int2* __restrict__ csr,
    const int* __restrict__ offs, const int* __restrict__ cnt,
    const float* __restrict__ dinv, const float* __restrict__ bias,
    const float* __restrict__ x, float* __restrict__ outbuf,
    float* __restrict__ partials, int n, int final_mode) {
    __shared__ float sh1[256][8];
    __shared__ float sh2[256][8];
    int tid = threadIdx.x;
    int node = blockIdx.x * 16 + (tid >> 4);
    int c = (tid & 15) * 8;
    bool valid = node < n;
    float a[8] = {0.f, 0.f, 0.f, 0.f, 0.f, 0.f, 0.f, 0.f};
    int e = 0, end = 0;
    if (valid) {
        float di = dinv[node];
        float w0 = di * di;
        bf16x8 hv = *(const bf16x8*)&h[(size_t)node * CH + c];
        #pragma unroll
        for (int j = 0; j < 8; ++j) a[j] = bf2f(hv[j]) * w0;
        e = offs[node];
        end = e + cnt[node];
    }

    for (; e + 4 <= end; e += 4) {
        int2 p0 = csr[e], p1 = csr[e + 1], p2 = csr[e + 2], p3 = csr[e + 3];
        bf16x8 v0 = *(const bf16x8*)&h[(size_t)p0.x * CH + c];
        bf16x8 v1 = *(const bf16x8*)&h[(size_t)p1.x * CH + c];
        bf16x8 v2 = *(const bf16x8*)&h[(size_t)p2.x * CH + c];
        bf16x8 v3 = *(const bf16x8*)&h[(size_t)p3.x * CH + c];
        float n0 = __int_as_float(p0.y), n1 = __int_as_float(p1.y);
        float n2 = __int_as_float(p2.y), n3 = __int_as_float(p3.y);
        #pragma unroll
        for (int j = 0; j < 8; ++j) {
            a[j] += bf2f(v0[j]) * n0;
            a[j] += bf2f(v1[j]) * n1;
            a[j] += bf2f(v2[j]) * n2;
            a[j] += bf2f(v3[j]) * n3;
        }
    }
    for (; e < end; ++e) {
        int2 p0 = csr[e];
        float n0 = __int_as_float(p0.y);
        bf16x8 v0 = *(const bf16x8*)&h[(size_t)p0.x * CH + c];
        #pragma unroll
        for (int j = 0; j < 8; ++j) a[j] += bf2f(v0[j]) * n0;
    }

    size_t o4 = (size_t)node * 32 + (c >> 2);
    if (final_mode) {
        if (valid) {
            f32x4 xb0 = nt_load4(&x[o4 * 4]);
            f32x4 xb1 = nt_load4(&x[o4 * 4 + 4]);
            f32x4 bb0 = *(const f32x4*)&bias[c];
            f32x4 bb1 = *(const f32x4*)&bias[c + 4];
            f32x4 o0, o1;
            o0[0] = fmaxf(a[0] + bb0[0], 0.f) + xb0[0];
            o0[1] = fmaxf(a[1] + bb0[1], 0.f) + xb0[1];
            o0[2] = fmaxf(a[2] + bb0[2], 0.f) + xb0[2];
            o0[3] = fmaxf(a[3] + bb0[3], 0.f) + xb0[3];
            o1[0] = fmaxf(a[4] + bb1[0], 0.f) + xb1[0];
            o1[1] = fmaxf(a[5] + bb1[1], 0.f) + xb1[1];
            o1[2] = fmaxf(a[6] + bb1[2], 0.f) + xb1[2];
            o1[3] = fmaxf(a[7] + bb1[3], 0.f) + xb1[3];
            nt_store4(&outbuf[o4 * 4], o0);
            nt_store4(&outbuf[o4 * 4 + 4], o1);
        }
    } else {
        if (valid) {
            f32x4 o0 = {a[0], a[1], a[2], a[3]};
            f32x4 o1 = {a[4], a[5], a[6], a[7]};
            nt_store4(&outbuf[o4 * 4], o0);
            nt_store4(&outbuf[o4 * 4 + 4], o1);
        }
        // fused stage-2 stats: relu(a + b1) per channel
        #pragma unroll
        for (int j = 0; j < 8; ++j) {
            float vv = valid ? fmaxf(a[j] + bias[c + j], 0.f) : 0.f;
            sh1[tid][j] = vv;
            sh2[tid][j] = vv * vv;
        }
        __syncthreads();
        if (tid < 128) {
            int lane16 = tid >> 3;
            int j = tid & 7;
            float s = 0.f, s2 = 0.f;
            #pragma unroll
            for (int g = 0; g < 16; ++g) {
                s  += sh1[g * 16 + lane16][j];
                s2 += sh2[g * 16 + lane16][j];
            }
            partials[(size_t)blockIdx.x * 256 + tid]       = s;
            partials[(size_t)blockIdx.x * 256 + 128 + tid] = s2;
        }
    }
}

extern "C" void kernel_launch(void* const* d_in, const int* in_sizes, int n_in,
                              void* d_out, int out_size, void* d_ws, size_t ws_size,
                              hipStream_t stream) {
    const float* x      = (const float*)d_in[0];
    const int*   eidx   = (const int*)d_in[1];
    const float* W1     = (const float*)d_in[2];
    const float* b1     = (const float*)d_in[3];
    const float* W2     = (const float*)d_in[4];
    const float* b2     = (const float*)d_in[5];
    const float* gamma1 = (const float*)d_in[6];
    const float* beta1  = (const float*)d_in[7];
    const float* gamma2 = (const float*)d_in[8];
    const float* beta2  = (const float*)d_in[9];
    float* out = (float*)d_out;

    const int N = in_sizes[0] / CH;
    const int E = in_sizes[1] / 2;
    const int* src = eidx;
    const int* dst = eidx + E;

    const int NAGG = (N + 15) / 16;

    char* ws = (char*)d_ws;
    size_t off = 0;
    auto carve = [&](size_t bytes) { char* p = ws + off; off = (off + bytes + 1023) & ~(size_t)1023; return p; };
    int*    cnt      = (int*)carve((size_t)(N + 1) * 4);  // cnt[N] = scan cursor
    float*  dinv     = (float*)carve((size_t)N * 4);
    int*    offs     = (int*)carve((size_t)N * 4);
    int*    slot     = (int*)carve((size_t)E * 4);
    float*  small    = (float*)carve(8 * CH * 4);
    float*  partials = (float*)carve((size_t)NAGG * 256 * 4);  // max(stats 1024, agg 6250)
    int2*   csr      = (int2*)carve((size_t)E * 8);
    __bf16* W1b      = (__bf16*)carve((size_t)CH * CH * 2);
    __bf16* W2b      = (__bf16*)carve((size_t)CH * CH * 2);
    __bf16* h_bf     = (__bf16*)carve((size_t)N * CH * 2);
    float*  agg_buf  = (float*)carve((size_t)N * CH * 4);
    float* sums1  = small + 0 * CH;
    float* sums2  = small + 2 * CH;
    float* scale1 = small + 4 * CH;
    float* shift1 = small + 5 * CH;
    float* scale2 = small + 6 * CH;
    float* shift2 = small + 7 * CH;
    (void)ws_size; (void)n_in; (void)out_size; (void)sums1; (void)sums2;

    int* cursor = cnt + N;
    hipMemsetAsync(cnt, 0, (size_t)(N + 1) * 4, stream);

    const int NB_COUNT = (E + 255) / 256;
    const int NB_STATS = STATS_BLOCKS;
    const int NB_WPREP = (2 * CH * CH + 255) / 256;
    const int NB_SCAN  = (N + 1023) / 1024;
    const int NB_DINV  = (N + 1023) / 1024;
    const int NB_FILL  = (E + 255) / 256;
    const int NB_GEMM  = (N + GROWS - 1) / GROWS;

    // K1: count + stats1(x) + weight bf16 prep
    k1_kernel<<<NB_COUNT + NB_STATS + NB_WPREP, 256, 0, stream>>>(
        dst, cnt, slot, E, x, partials, N * 32, W1, W2, W1b, W2b,
        NB_COUNT, NB_STATS);

    // K2: scan(atomic base) + dinv + reduce1/bnparam1
    k2_kernel<<<NB_SCAN + NB_DINV + 16, 256, 0, stream>>>(
        cnt, offs, cursor, dinv, N, partials, gamma1, beta1,
        scale1, shift1, STATS_BLOCKS, NB_SCAN, NB_DINV);

    // K3: fill CSR + gemm1
    k3_kernel<<<NB_FILL + NB_GEMM, 256, 0, stream>>>(
        src, dst, slot, offs, dinv, csr, E,
        x, scale1, shift1, W1b, h_bf, N, NB_FILL);

    // agg1 + fused stats2 partials
    agg_kernel<<<NAGG, 256, 0, stream>>>(h_bf, csr, offs, cnt, dinv,
                                         b1, nullptr, agg_buf, partials, N, 0);

    // reduce2 + bnparam2
    reducebn_kernel<<<16, 256, 0, stream>>>(partials, NAGG, gamma2, beta2,
                                            scale2, shift2, N);

    // gemm2 (nontemporal A read: last use of agg_buf)
    gemm_kernel<<<NB_GEMM, 256, 0, stream>>>(agg_buf, b1, 1, scale2, shift2,
                                             W2b, h_bf, N, 1);

    // agg2: final relu + bias + residual
    agg_kernel<<<NAGG, 256, 0, stream>>>(h_bf, csr, offs, cnt, dinv,
                                         b2, x, out, nullptr, N, 1);
}

// Round 2
// 451.354 us; speedup vs baseline: 1.0247x; 1.0247x over previous
//
#include <hip/hip_runtime.h>
#include <hip/hip_bf16.h>
#include <cstddef>

#define CH 128
#define BN_EPS 1e-5f
#define STATS_BLOCKS 1024

typedef __bf16 bf16x8 __attribute__((ext_vector_type(8)));
typedef __bf16 bf16x4 __attribute__((ext_vector_type(4)));
typedef float  f32x4  __attribute__((ext_vector_type(4)));

__device__ inline float bf2f(__bf16 b) { return (float)b; }

__device__ inline f32x4 nt_load4(const float* p) {
    return __builtin_nontemporal_load((const f32x4*)p);
}
__device__ inline void nt_store4(float* p, f32x4 v) {
    __builtin_nontemporal_store(v, (f32x4*)p);
}

// ---------------------------------------------------------------------------
// R8: revert the one measured regression from R7 (k3 fill+gemm fusion:
// 71.9us fused vs ~40-45us separate -- latency-bound scatter blocks
// interfering with LDS/MFMA blocks). fill and gemm are standalone again.
// agg_buf store back to regular (it IS re-read by gemm2; nt was wrong).
// Keep R7's wins: k1 (count+stats1+wprep), k2 (scan+dinv+reducebn1),
// stats2 fused into agg1, single-kernel atomic-base scan, nt for out/x-last.
// ---------------------------------------------------------------------------

// ---- K1: count (atomics) + stats1 over x + wprep W1,W2 -> bf16 -------------
__global__ __launch_bounds__(256) void k1_kernel(
    const int* __restrict__ dst, int* __restrict__ cnt, int* __restrict__ slot, int E,
    const float* __restrict__ x, float* __restrict__ partials, int total4,
    const float* __restrict__ W1, const float* __restrict__ W2,
    __bf16* __restrict__ W1b, __bf16* __restrict__ W2b,
    int NB_COUNT, int NB_STATS) {
    int b = blockIdx.x;
    if (b < NB_COUNT) {
        int e = b * 256 + threadIdx.x;
        if (e < E) slot[e] = atomicAdd(&cnt[dst[e]], 1);
    } else if (b < NB_COUNT + NB_STATS) {
        // per-channel sum & sumsq -> per-block partial row (sums||sumsq)
        int sbid = b - NB_COUNT;
        int l = threadIdx.x & 31;
        int g = threadIdx.x >> 5;
        float4 s  = make_float4(0.f, 0.f, 0.f, 0.f);
        float4 s2 = make_float4(0.f, 0.f, 0.f, 0.f);
        int gid = sbid * 256 + threadIdx.x;
        int gs = NB_STATS * 256;
        const float4* in4 = (const float4*)x;

        auto accum = [&](float4 v) {
            s.x += v.x; s.y += v.y; s.z += v.z; s.w += v.w;
            s2.x += v.x * v.x; s2.y += v.y * v.y; s2.z += v.z * v.z; s2.w += v.w * v.w;
        };

        int i = gid;
        for (; i + 3 * gs < total4; i += 4 * gs) {
            float4 v0 = in4[i];
            float4 v1 = in4[i + gs];
            float4 v2 = in4[i + 2 * gs];
            float4 v3 = in4[i + 3 * gs];
            accum(v0); accum(v1); accum(v2); accum(v3);
        }
        for (; i < total4; i += gs) accum(in4[i]);

        __shared__ float4 ls[8][32], ls2[8][32];
        ls[g][l] = s; ls2[g][l] = s2;
        __syncthreads();
        if (g == 0) {
            #pragma unroll
            for (int k = 1; k < 8; ++k) {
                float4 a = ls[k][l], bb = ls2[k][l];
                s.x += a.x; s.y += a.y; s.z += a.z; s.w += a.w;
                s2.x += bb.x; s2.y += bb.y; s2.z += bb.z; s2.w += bb.w;
            }
            ((float4*)partials)[sbid * 64 + l]      = s;
            ((float4*)partials)[sbid * 64 + 32 + l] = s2;
        }
    } else {
        int i = (b - NB_COUNT - NB_STATS) * 256 + threadIdx.x;
        if (i < CH * CH) W1b[i] = (__bf16)W1[i];
        else if (i < 2 * CH * CH) W2b[i - CH * CH] = (__bf16)W2[i - CH * CH];
    }
}

// ---- reduce partial rows + BN params (8 channels per block, 16 blocks) -----
__device__ inline void reducebn_body(
    int blk, const float* __restrict__ partials, int R,
    const float* __restrict__ gamma, const float* __restrict__ beta,
    float* __restrict__ scale, float* __restrict__ shift, float inv_n) {
    __shared__ float l1[256], l2[256];
    int t = threadIdx.x;
    int cl = t & 7;
    int r0 = t >> 3;
    int c = blk * 8 + cl;
    float a1 = 0.f, a2 = 0.f;
    for (int r = r0; r < R; r += 32) {
        a1 += partials[(size_t)r * 256 + c];
        a2 += partials[(size_t)r * 256 + 128 + c];
    }
    l1[t] = a1; l2[t] = a2;
    __syncthreads();
    #pragma unroll
    for (int off = 16; off >= 1; off >>= 1) {
        if (r0 < off) {
            l1[t] += l1[t + off * 8];
            l2[t] += l2[t + off * 8];
        }
        __syncthreads();
    }
    if (t < 8) {
        float mean = l1[t] * inv_n;
        float var  = l2[t] * inv_n - mean * mean;  // biased
        float sc = gamma[c] * rsqrtf(var + BN_EPS);
        scale[c] = sc;
        shift[c] = beta[c] - mean * sc;
    }
}

// ---- K2: atomic-base scan + dinv + reduce1/bnparam1 ------------------------
__global__ __launch_bounds__(256) void k2_kernel(
    const int* __restrict__ cnt, int* __restrict__ offs, int* __restrict__ cursor,
    float* __restrict__ dinv, int n,
    const float* __restrict__ partials,
    const float* __restrict__ gamma1, const float* __restrict__ beta1,
    float* __restrict__ scale1, float* __restrict__ shift1,
    int R, int NB_SCAN, int NB_DINV) {
    int b = blockIdx.x;
    if (b < NB_SCAN) {
        __shared__ int sd[256];
        __shared__ int sbase;
        int t = threadIdx.x;
        int base = b * 1024 + t * 4;
        int v[4];
        #pragma unroll
        for (int j = 0; j < 4; ++j) v[j] = (base + j < n) ? cnt[base + j] : 0;
        int s = v[0] + v[1] + v[2] + v[3];
        sd[t] = s;
        __syncthreads();
        for (int off = 1; off < 256; off <<= 1) {
            int xv = (t >= off) ? sd[t - off] : 0;
            __syncthreads();
            sd[t] += xv;
            __syncthreads();
        }
        if (t == 255) sbase = atomicAdd(cursor, sd[255]);
        __syncthreads();
        int run = sbase + sd[t] - s;
        #pragma unroll
        for (int j = 0; j < 4; ++j) {
            if (base + j < n) offs[base + j] = run;
            run += v[j];
        }
    } else if (b < NB_SCAN + NB_DINV) {
        int ib = (b - NB_SCAN) * 1024 + threadIdx.x * 4;
        #pragma unroll
        for (int j = 0; j < 4; ++j) {
            int i = ib + j;
            if (i < n) dinv[i] = rsqrtf((float)cnt[i] + 1.0f);  // +1 self loop
        }
    } else {
        reducebn_body(b - NB_SCAN - NB_DINV, partials, R, gamma1, beta1,
                      scale1, shift1, 1.0f / (float)n);
    }
}

__global__ __launch_bounds__(256) void reducebn_kernel(
    const float* __restrict__ partials, int R,
    const float* __restrict__ gamma, const float* __restrict__ beta,
    float* __restrict__ scale, float* __restrict__ shift, int n) {
    reducebn_body(blockIdx.x, partials, R, gamma, beta, scale, shift, 1.0f / (float)n);
}

// ---- fill CSR (standalone: latency-bound scatter, wants max occupancy) -----
__global__ void fill_kernel(const int* __restrict__ src, const int* __restrict__ dst,
                            const int* __restrict__ slot, const int* __restrict__ offs,
                            const float* __restrict__ dinv, int2* __restrict__ csr, int E) {
    int e = blockIdx.x * 256 + threadIdx.x;
    if (e >= E) return;
    int s = src[e], d = dst[e];
    int p = offs[d] + slot[e];
    float nrm = dinv[s] * dinv[d];
    csr[p] = make_int2(s, __float_as_int(nrm));
}

// ---- MFMA GEMM (standalone) ------------------------------------------------
#define GROWS 64
#define LDA 136

__global__ __launch_bounds__(256) void gemm_kernel(
    const float* __restrict__ A, const float* __restrict__ bias, int do_relu,
    const float* __restrict__ scale, const float* __restrict__ shift,
    const __bf16* __restrict__ Wb, __bf16* __restrict__ Hout, int n, int ntA) {
    __shared__ __bf16 As[GROWS][LDA];
    int tid = threadIdx.x;
    int row0 = blockIdx.x * GROWS;

    #pragma unroll
    for (int p = 0; p < 8; ++p) {
        int idx = p * 256 + tid;
        int r = idx >> 5;
        int f4 = idx & 31;
        int c4 = f4 * 4;
        int row = row0 + r;
        f32x4 v = {0.f, 0.f, 0.f, 0.f};
        if (row < n) {
            const f32x4* p4 = (const f32x4*)A + ((size_t)row * 32 + f4);
            v = ntA ? __builtin_nontemporal_load(p4) : *p4;
        }
        __bf16 u[4];
        #pragma unroll
        for (int j = 0; j < 4; ++j) {
            int ch = c4 + j;
            float f = v[j];
            if (do_relu) f = fmaxf(f + bias[ch], 0.f);
            f = f * scale[ch] + shift[ch];
            u[j] = (__bf16)f;
        }
        *(bf16x4*)&As[r][c4] = *(bf16x4*)u;
    }
    __syncthreads();

    int wv = tid >> 6;
    int lane = tid & 63;
    int m = lane & 15;
    int q = lane >> 4;
    int arow = wv * 16 + m;
    f32x4 acc[8] = {};
    #pragma unroll
    for (int kc = 0; kc < CH; kc += 32) {
        bf16x8 af = *(const bf16x8*)&As[arow][kc + q * 8];
        #pragma unroll
        for (int t = 0; t < 8; ++t) {
            bf16x8 bf = *(const bf16x8*)&Wb[(size_t)(t * 16 + m) * CH + kc + q * 8];
            acc[t] = __builtin_amdgcn_mfma_f32_16x16x32_bf16(af, bf, acc[t], 0, 0, 0);
        }
    }

    #pragma unroll
    for (int t = 0; t < 8; ++t) {
        #pragma unroll
        for (int r = 0; r < 4; ++r) {
            int row = row0 + wv * 16 + q * 4 + r;
            if (row < n) Hout[(size_t)row * CH + t * 16 + m] = (__bf16)acc[t][r];
        }
    }
}

// ---------------------------------------------------------------------------
// Gather aggregation: 16 lanes/node, 8 ch/lane, 16 nodes/block.
// mode 0: writes agg_buf (regular store: re-read by gemm2) + fused stage-2
//         stats partial row per block.
// mode 1: final relu + bias + residual, nt store to out (never re-read).
// ---------------------------------------------------------------------------
__global__ __launch_bounds__(256) void agg_kernel(
    const __bf16* __restrict__ h, const int2* __restrict__ csr,
    const int* __restrict__ offs, const int* __restrict__ cnt,
    const float* __restrict__ dinv, const float* __restrict__ bias,
    const float* __restrict__ x, float* __restrict__ outbuf,
    float* __restrict__ partials, int n, int final_mode) {
    __shared__ float sh1[256][8];
    __shared__ float sh2[256][8];
    int tid = threadIdx.x;
    int node = blockIdx.x * 16 + (tid >> 4);
    int c = (tid & 15) * 8;
    bool valid = node < n;
    float a[8] = {0.f, 0.f, 0.f, 0.f, 0.f, 0.f, 0.f, 0.f};
    int e = 0, end = 0;
    if (valid) {
        float di = dinv[node];
        float w0 = di * di;
        bf16x8 hv = *(const bf16x8*)&h[(size_t)node * CH + c];
        #pragma unroll
        for (int j = 0; j < 8; ++j) a[j] = bf2f(hv[j]) * w0;
        e = offs[node];
        end = e + cnt[node];
    }

    for (; e + 4 <= end; e += 4) {
        int2 p0 = csr[e], p1 = csr[e + 1], p2 = csr[e + 2], p3 = csr[e + 3];
        bf16x8 v0 = *(const bf16x8*)&h[(size_t)p0.x * CH + c];
        bf16x8 v1 = *(const bf16x8*)&h[(size_t)p1.x * CH + c];
        bf16x8 v2 = *(const bf16x8*)&h[(size_t)p2.x * CH + c];
        bf16x8 v3 = *(const bf16x8*)&h[(size_t)p3.x * CH + c];
        float n0 = __int_as_float(p0.y), n1 = __int_as_float(p1.y);
        float n2 = __int_as_float(p2.y), n3 = __int_as_float(p3.y);
        #pragma unroll
        for (int j = 0; j < 8; ++j) {
            a[j] += bf2f(v0[j]) * n0;
            a[j] += bf2f(v1[j]) * n1;
            a[j] += bf2f(v2[j]) * n2;
            a[j] += bf2f(v3[j]) * n3;
        }
    }
    for (; e < end; ++e) {
        int2 p0 = csr[e];
        float n0 = __int_as_float(p0.y);
        bf16x8 v0 = *(const bf16x8*)&h[(size_t)p0.x * CH + c];
        #pragma unroll
        for (int j = 0; j < 8; ++j) a[j] += bf2f(v0[j]) * n0;
    }

    size_t o4 = (size_t)node * 32 + (c >> 2);
    if (final_mode) {
        if (valid) {
            f32x4 xb0 = nt_load4(&x[o4 * 4]);
            f32x4 xb1 = nt_load4(&x[o4 * 4 + 4]);
            f32x4 bb0 = *(const f32x4*)&bias[c];
            f32x4 bb1 = *(const f32x4*)&bias[c + 4];
            f32x4 o0, o1;
            o0[0] = fmaxf(a[0] + bb0[0], 0.f) + xb0[0];
            o0[1] = fmaxf(a[1] + bb0[1], 0.f) + xb0[1];
            o0[2] = fmaxf(a[2] + bb0[2], 0.f) + xb0[2];
            o0[3] = fmaxf(a[3] + bb0[3], 0.f) + xb0[3];
            o1[0] = fmaxf(a[4] + bb1[0], 0.f) + xb1[0];
            o1[1] = fmaxf(a[5] + bb1[1], 0.f) + xb1[1];
            o1[2] = fmaxf(a[6] + bb1[2], 0.f) + xb1[2];
            o1[3] = fmaxf(a[7] + bb1[3], 0.f) + xb1[3];
            nt_store4(&outbuf[o4 * 4], o0);
            nt_store4(&outbuf[o4 * 4 + 4], o1);
        }
    } else {
        if (valid) {
            ((float4*)outbuf)[o4]     = make_float4(a[0], a[1], a[2], a[3]);
            ((float4*)outbuf)[o4 + 1] = make_float4(a[4], a[5], a[6], a[7]);
        }
        // fused stage-2 stats: relu(a + b1) per channel
        #pragma unroll
        for (int j = 0; j < 8; ++j) {
            float vv = valid ? fmaxf(a[j] + bias[c + j], 0.f) : 0.f;
            sh1[tid][j] = vv;
            sh2[tid][j] = vv * vv;
        }
        __syncthreads();
        if (tid < 128) {
            int lane16 = tid >> 3;
            int j = tid & 7;
            float s = 0.f, s2 = 0.f;
            #pragma unroll
            for (int g = 0; g < 16; ++g) {
                s  += sh1[g * 16 + lane16][j];
                s2 += sh2[g * 16 + lane16][j];
            }
            partials[(size_t)blockIdx.x * 256 + tid]       = s;
            partials[(size_t)blockIdx.x * 256 + 128 + tid] = s2;
        }
    }
}

extern "C" void kernel_launch(void* const* d_in, const int* in_sizes, int n_in,
                              void* d_out, int out_size, void* d_ws, size_t ws_size,
                              hipStream_t stream) {
    const float* x      = (const float*)d_in[0];
    const int*   eidx   = (const int*)d_in[1];
    const float* W1     = (const float*)d_in[2];
    const float* b1     = (const float*)d_in[3];
    const float* W2     = (const float*)d_in[4];
    const float* b2     = (const float*)d_in[5];
    const float* gamma1 = (const float*)d_in[6];
    const float* beta1  = (const float*)d_in[7];
    const float* gamma2 = (const float*)d_in[8];
    const float* beta2  = (const float*)d_in[9];
    float* out = (float*)d_out;

    const int N = in_sizes[0] / CH;
    const int E = in_sizes[1] / 2;
    const int* src = eidx;
    const int* dst = eidx + E;

    const int NAGG = (N + 15) / 16;

    char* ws = (char*)d_ws;
    size_t off = 0;
    auto carve = [&](size_t bytes) { char* p = ws + off; off = (off + bytes + 1023) & ~(size_t)1023; return p; };
    int*    cnt      = (int*)carve((size_t)(N + 1) * 4);  // cnt[N] = scan cursor
    float*  dinv     = (float*)carve((size_t)N * 4);
    int*    offs     = (int*)carve((size_t)N * 4);
    int*    slot     = (int*)carve((size_t)E * 4);
    float*  small    = (float*)carve(8 * CH * 4);
    float*  partials = (float*)carve((size_t)NAGG * 256 * 4);  // max(stats 1024, agg 6250)
    int2*   csr      = (int2*)carve((size_t)E * 8);
    __bf16* W1b      = (__bf16*)carve((size_t)CH * CH * 2);
    __bf16* W2b      = (__bf16*)carve((size_t)CH * CH * 2);
    __bf16* h_bf     = (__bf16*)carve((size_t)N * CH * 2);
    float*  agg_buf  = (float*)carve((size_t)N * CH * 4);
    float* scale1 = small + 4 * CH;
    float* shift1 = small + 5 * CH;
    float* scale2 = small + 6 * CH;
    float* shift2 = small + 7 * CH;
    (void)ws_size; (void)n_in; (void)out_size;

    int* cursor = cnt + N;
    hipMemsetAsync(cnt, 0, (size_t)(N + 1) * 4, stream);

    const int NB_COUNT = (E + 255) / 256;
    const int NB_STATS = STATS_BLOCKS;
    const int NB_WPREP = (2 * CH * CH + 255) / 256;
    const int NB_SCAN  = (N + 1023) / 1024;
    const int NB_DINV  = (N + 1023) / 1024;
    const int NB_FILL  = (E + 255) / 256;
    const int NB_GEMM  = (N + GROWS - 1) / GROWS;

    // K1: count + stats1(x) + weight bf16 prep
    k1_kernel<<<NB_COUNT + NB_STATS + NB_WPREP, 256, 0, stream>>>(
        dst, cnt, slot, E, x, partials, N * 32, W1, W2, W1b, W2b,
        NB_COUNT, NB_STATS);

    // K2: scan(atomic base) + dinv + reduce1/bnparam1
    k2_kernel<<<NB_SCAN + NB_DINV + 16, 256, 0, stream>>>(
        cnt, offs, cursor, dinv, N, partials, gamma1, beta1,
        scale1, shift1, STATS_BLOCKS, NB_SCAN, NB_DINV);

    // fill CSR (standalone, max occupancy for the random scatter)
    fill_kernel<<<NB_FILL, 256, 0, stream>>>(src, dst, slot, offs, dinv, csr, E);

    // gemm1 (standalone MFMA)
    gemm_kernel<<<NB_GEMM, 256, 0, stream>>>(x, nullptr, 0, scale1, shift1,
                                             W1b, h_bf, N, 0);

    // agg1 + fused stats2 partials
    agg_kernel<<<NAGG, 256, 0, stream>>>(h_bf, csr, offs, cnt, dinv,
                                         b1, nullptr, agg_buf, partials, N, 0);

    // reduce2 + bnparam2
    reducebn_kernel<<<16, 256, 0, stream>>>(partials, NAGG, gamma2, beta2,
                                            scale2, shift2, N);

    // gemm2 (nontemporal A read: last use of agg_buf)
    gemm_kernel<<<NB_GEMM, 256, 0, stream>>>(agg_buf, b1, 1, scale2, shift2,
                                             W2b, h_bf, N, 1);

    // agg2: final relu + bias + residual
    agg_kernel<<<NAGG, 256, 0, stream>>>(h_bf, csr, offs, cnt, dinv,
                                         b2, x, out, nullptr, N, 1);
}

// Round 3
// 404.112 us; speedup vs baseline: 1.1445x; 1.1169x over previous
//
#include <hip/hip_runtime.h>
#include <hip/hip_bf16.h>
#include <cstddef>

#define CH 128
#define BN_EPS 1e-5f
#define STATS_BLOCKS 256
#define FOLD_BLOCKS 256

typedef __bf16 bf16x8 __attribute__((ext_vector_type(8)));
typedef __bf16 bf16x4 __attribute__((ext_vector_type(4)));
typedef float  f32x4  __attribute__((ext_vector_type(4)));

__device__ inline float bf2f(__bf16 b) { return (float)b; }

__device__ inline f32x4 nt_load4(const float* p) {
    return __builtin_nontemporal_load((const f32x4*)p);
}
__device__ inline void nt_store4(float* p, f32x4 v) {
    __builtin_nontemporal_store(v, (f32x4*)p);
}

// ---------------------------------------------------------------------------
// R9: kill the 62us reducebn (R=6250, 16 blocks, 0.65% occupancy, 206 GB/s
// latency chain -- rocprof R8 top-1). Fix = parallel fold: 256-block tree
// reduce of partial rows -> 256 rows, then reducebn reads 0.25MB instead of
// 12.5MB. Also STATS_BLOCKS 1024->256 so stage-1 reducebn (in k2) reads 4x
// less. Everything else = R8 (which fixed R7's fill+gemm fusion regression).
// ---------------------------------------------------------------------------

// ---- K1: count (atomics) + stats1 over x + wprep W1,W2 -> bf16 -------------
__global__ __launch_bounds__(256) void k1_kernel(
    const int* __restrict__ dst, int* __restrict__ cnt, int* __restrict__ slot, int E,
    const float* __restrict__ x, float* __restrict__ partials, int total4,
    const float* __restrict__ W1, const float* __restrict__ W2,
    __bf16* __restrict__ W1b, __bf16* __restrict__ W2b,
    int NB_COUNT, int NB_STATS) {
    int b = blockIdx.x;
    if (b < NB_COUNT) {
        int e = b * 256 + threadIdx.x;
        if (e < E) slot[e] = atomicAdd(&cnt[dst[e]], 1);
    } else if (b < NB_COUNT + NB_STATS) {
        // per-channel sum & sumsq -> per-block partial row (sums||sumsq)
        int sbid = b - NB_COUNT;
        int l = threadIdx.x & 31;
        int g = threadIdx.x >> 5;
        float4 s  = make_float4(0.f, 0.f, 0.f, 0.f);
        float4 s2 = make_float4(0.f, 0.f, 0.f, 0.f);
        int gid = sbid * 256 + threadIdx.x;
        int gs = NB_STATS * 256;
        const float4* in4 = (const float4*)x;

        auto accum = [&](float4 v) {
            s.x += v.x; s.y += v.y; s.z += v.z; s.w += v.w;
            s2.x += v.x * v.x; s2.y += v.y * v.y; s2.z += v.z * v.z; s2.w += v.w * v.w;
        };

        int i = gid;
        for (; i + 3 * gs < total4; i += 4 * gs) {
            float4 v0 = in4[i];
            float4 v1 = in4[i + gs];
            float4 v2 = in4[i + 2 * gs];
            float4 v3 = in4[i + 3 * gs];
            accum(v0); accum(v1); accum(v2); accum(v3);
        }
        for (; i < total4; i += gs) accum(in4[i]);

        __shared__ float4 ls[8][32], ls2[8][32];
        ls[g][l] = s; ls2[g][l] = s2;
        __syncthreads();
        if (g == 0) {
            #pragma unroll
            for (int k = 1; k < 8; ++k) {
                float4 a = ls[k][l], bb = ls2[k][l];
                s.x += a.x; s.y += a.y; s.z += a.z; s.w += a.w;
                s2.x += bb.x; s2.y += bb.y; s2.z += bb.z; s2.w += bb.w;
            }
            ((float4*)partials)[sbid * 64 + l]      = s;
            ((float4*)partials)[sbid * 64 + 32 + l] = s2;
        }
    } else {
        int i = (b - NB_COUNT - NB_STATS) * 256 + threadIdx.x;
        if (i < CH * CH) W1b[i] = (__bf16)W1[i];
        else if (i < 2 * CH * CH) W2b[i - CH * CH] = (__bf16)W2[i - CH * CH];
    }
}

// ---- reduce partial rows + BN params (8 channels per block, 16 blocks) -----
__device__ inline void reducebn_body(
    int blk, const float* __restrict__ partials, int R,
    const float* __restrict__ gamma, const float* __restrict__ beta,
    float* __restrict__ scale, float* __restrict__ shift, float inv_n) {
    __shared__ float l1[256], l2[256];
    int t = threadIdx.x;
    int cl = t & 7;
    int r0 = t >> 3;
    int c = blk * 8 + cl;
    float a1 = 0.f, a2 = 0.f;
    for (int r = r0; r < R; r += 32) {
        a1 += partials[(size_t)r * 256 + c];
        a2 += partials[(size_t)r * 256 + 128 + c];
    }
    l1[t] = a1; l2[t] = a2;
    __syncthreads();
    #pragma unroll
    for (int off = 16; off >= 1; off >>= 1) {
        if (r0 < off) {
            l1[t] += l1[t + off * 8];
            l2[t] += l2[t + off * 8];
        }
        __syncthreads();
    }
    if (t < 8) {
        float mean = l1[t] * inv_n;
        float var  = l2[t] * inv_n - mean * mean;  // biased
        float sc = gamma[c] * rsqrtf(var + BN_EPS);
        scale[c] = sc;
        shift[c] = beta[c] - mean * sc;
    }
}

// ---- K2: atomic-base scan + dinv + reduce1/bnparam1 ------------------------
__global__ __launch_bounds__(256) void k2_kernel(
    const int* __restrict__ cnt, int* __restrict__ offs, int* __restrict__ cursor,
    float* __restrict__ dinv, int n,
    const float* __restrict__ partials,
    const float* __restrict__ gamma1, const float* __restrict__ beta1,
    float* __restrict__ scale1, float* __restrict__ shift1,
    int R, int NB_SCAN, int NB_DINV) {
    int b = blockIdx.x;
    if (b < NB_SCAN) {
        __shared__ int sd[256];
        __shared__ int sbase;
        int t = threadIdx.x;
        int base = b * 1024 + t * 4;
        int v[4];
        #pragma unroll
        for (int j = 0; j < 4; ++j) v[j] = (base + j < n) ? cnt[base + j] : 0;
        int s = v[0] + v[1] + v[2] + v[3];
        sd[t] = s;
        __syncthreads();
        for (int off = 1; off < 256; off <<= 1) {
            int xv = (t >= off) ? sd[t - off] : 0;
            __syncthreads();
            sd[t] += xv;
            __syncthreads();
        }
        if (t == 255) sbase = atomicAdd(cursor, sd[255]);
        __syncthreads();
        int run = sbase + sd[t] - s;
        #pragma unroll
        for (int j = 0; j < 4; ++j) {
            if (base + j < n) offs[base + j] = run;
            run += v[j];
        }
    } else if (b < NB_SCAN + NB_DINV) {
        int ib = (b - NB_SCAN) * 1024 + threadIdx.x * 4;
        #pragma unroll
        for (int j = 0; j < 4; ++j) {
            int i = ib + j;
            if (i < n) dinv[i] = rsqrtf((float)cnt[i] + 1.0f);  // +1 self loop
        }
    } else {
        reducebn_body(b - NB_SCAN - NB_DINV, partials, R, gamma1, beta1,
                      scale1, shift1, 1.0f / (float)n);
    }
}

__global__ __launch_bounds__(256) void reducebn_kernel(
    const float* __restrict__ partials, int R,
    const float* __restrict__ gamma, const float* __restrict__ beta,
    float* __restrict__ scale, float* __restrict__ shift, int n) {
    reducebn_body(blockIdx.x, partials, R, gamma, beta, scale, shift, 1.0f / (float)n);
}

// ---- fold: R partial rows -> FOLD_BLOCKS rows (coalesced full-row reads) ---
__global__ __launch_bounds__(256) void fold_kernel(
    const float* __restrict__ partials, float* __restrict__ out, int R) {
    int t = threadIdx.x;
    float acc = 0.f;
    for (int r = blockIdx.x; r < R; r += FOLD_BLOCKS)
        acc += __builtin_nontemporal_load(&partials[(size_t)r * 256 + t]);
    out[(size_t)blockIdx.x * 256 + t] = acc;
}

// ---- fill CSR (standalone: latency-bound scatter, wants max occupancy) -----
__global__ void fill_kernel(const int* __restrict__ src, const int* __restrict__ dst,
                            const int* __restrict__ slot, const int* __restrict__ offs,
                            const float* __restrict__ dinv, int2* __restrict__ csr, int E) {
    int e = blockIdx.x * 256 + threadIdx.x;
    if (e >= E) return;
    int s = src[e], d = dst[e];
    int p = offs[d] + slot[e];
    float nrm = dinv[s] * dinv[d];
    csr[p] = make_int2(s, __float_as_int(nrm));
}

// ---- MFMA GEMM (standalone) ------------------------------------------------
#define GROWS 64
#define LDA 136

__global__ __launch_bounds__(256) void gemm_kernel(
    const float* __restrict__ A, const float* __restrict__ bias, int do_relu,
    const float* __restrict__ scale, const float* __restrict__ shift,
    const __bf16* __restrict__ Wb, __bf16* __restrict__ Hout, int n, int ntA) {
    __shared__ __bf16 As[GROWS][LDA];
    int tid = threadIdx.x;
    int row0 = blockIdx.x * GROWS;

    #pragma unroll
    for (int p = 0; p < 8; ++p) {
        int idx = p * 256 + tid;
        int r = idx >> 5;
        int f4 = idx & 31;
        int c4 = f4 * 4;
        int row = row0 + r;
        f32x4 v = {0.f, 0.f, 0.f, 0.f};
        if (row < n) {
            const f32x4* p4 = (const f32x4*)A + ((size_t)row * 32 + f4);
            v = ntA ? __builtin_nontemporal_load(p4) : *p4;
        }
        __bf16 u[4];
        #pragma unroll
        for (int j = 0; j < 4; ++j) {
            int ch = c4 + j;
            float f = v[j];
            if (do_relu) f = fmaxf(f + bias[ch], 0.f);
            f = f * scale[ch] + shift[ch];
            u[j] = (__bf16)f;
        }
        *(bf16x4*)&As[r][c4] = *(bf16x4*)u;
    }
    __syncthreads();

    int wv = tid >> 6;
    int lane = tid & 63;
    int m = lane & 15;
    int q = lane >> 4;
    int arow = wv * 16 + m;
    f32x4 acc[8] = {};
    #pragma unroll
    for (int kc = 0; kc < CH; kc += 32) {
        bf16x8 af = *(const bf16x8*)&As[arow][kc + q * 8];
        #pragma unroll
        for (int t = 0; t < 8; ++t) {
            bf16x8 bf = *(const bf16x8*)&Wb[(size_t)(t * 16 + m) * CH + kc + q * 8];
            acc[t] = __builtin_amdgcn_mfma_f32_16x16x32_bf16(af, bf, acc[t], 0, 0, 0);
        }
    }

    #pragma unroll
    for (int t = 0; t < 8; ++t) {
        #pragma unroll
        for (int r = 0; r < 4; ++r) {
            int row = row0 + wv * 16 + q * 4 + r;
            if (row < n) Hout[(size_t)row * CH + t * 16 + m] = (__bf16)acc[t][r];
        }
    }
}

// ---------------------------------------------------------------------------
// Gather aggregation: 16 lanes/node, 8 ch/lane, 16 nodes/block.
// mode 0: writes agg_buf (regular store: re-read by gemm2) + fused stage-2
//         stats partial row per block.
// mode 1: final relu + bias + residual, nt store to out (never re-read).
// ---------------------------------------------------------------------------
__global__ __launch_bounds__(256) void agg_kernel(
    const __bf16* __restrict__ h, const int2* __restrict__ csr,
    const int* __restrict__ offs, const int* __restrict__ cnt,
    const float* __restrict__ dinv, const float* __restrict__ bias,
    const float* __restrict__ x, float* __restrict__ outbuf,
    float* __restrict__ partials, int n, int final_mode) {
    __shared__ float sh1[256][8];
    __shared__ float sh2[256][8];
    int tid = threadIdx.x;
    int node = blockIdx.x * 16 + (tid >> 4);
    int c = (tid & 15) * 8;
    bool valid = node < n;
    float a[8] = {0.f, 0.f, 0.f, 0.f, 0.f, 0.f, 0.f, 0.f};
    int e = 0, end = 0;
    if (valid) {
        float di = dinv[node];
        float w0 = di * di;
        bf16x8 hv = *(const bf16x8*)&h[(size_t)node * CH + c];
        #pragma unroll
        for (int j = 0; j < 8; ++j) a[j] = bf2f(hv[j]) * w0;
        e = offs[node];
        end = e + cnt[node];
    }

    for (; e + 4 <= end; e += 4) {
        int2 p0 = csr[e], p1 = csr[e + 1], p2 = csr[e + 2], p3 = csr[e + 3];
        bf16x8 v0 = *(const bf16x8*)&h[(size_t)p0.x * CH + c];
        bf16x8 v1 = *(const bf16x8*)&h[(size_t)p1.x * CH + c];
        bf16x8 v2 = *(const bf16x8*)&h[(size_t)p2.x * CH + c];
        bf16x8 v3 = *(const bf16x8*)&h[(size_t)p3.x * CH + c];
        float n0 = __int_as_float(p0.y), n1 = __int_as_float(p1.y);
        float n2 = __int_as_float(p2.y), n3 = __int_as_float(p3.y);
        #pragma unroll
        for (int j = 0; j < 8; ++j) {
            a[j] += bf2f(v0[j]) * n0;
            a[j] += bf2f(v1[j]) * n1;
            a[j] += bf2f(v2[j]) * n2;
            a[j] += bf2f(v3[j]) * n3;
        }
    }
    for (; e < end; ++e) {
        int2 p0 = csr[e];
        float n0 = __int_as_float(p0.y);
        bf16x8 v0 = *(const bf16x8*)&h[(size_t)p0.x * CH + c];
        #pragma unroll
        for (int j = 0; j < 8; ++j) a[j] += bf2f(v0[j]) * n0;
    }

    size_t o4 = (size_t)node * 32 + (c >> 2);
    if (final_mode) {
        if (valid) {
            f32x4 xb0 = nt_load4(&x[o4 * 4]);
            f32x4 xb1 = nt_load4(&x[o4 * 4 + 4]);
            f32x4 bb0 = *(const f32x4*)&bias[c];
            f32x4 bb1 = *(const f32x4*)&bias[c + 4];
            f32x4 o0, o1;
            o0[0] = fmaxf(a[0] + bb0[0], 0.f) + xb0[0];
            o0[1] = fmaxf(a[1] + bb0[1], 0.f) + xb0[1];
            o0[2] = fmaxf(a[2] + bb0[2], 0.f) + xb0[2];
            o0[3] = fmaxf(a[3] + bb0[3], 0.f) + xb0[3];
            o1[0] = fmaxf(a[4] + bb1[0], 0.f) + xb1[0];
            o1[1] = fmaxf(a[5] + bb1[1], 0.f) + xb1[1];
            o1[2] = fmaxf(a[6] + bb1[2], 0.f) + xb1[2];
            o1[3] = fmaxf(a[7] + bb1[3], 0.f) + xb1[3];
            nt_store4(&outbuf[o4 * 4], o0);
            nt_store4(&outbuf[o4 * 4 + 4], o1);
        }
    } else {
        if (valid) {
            ((float4*)outbuf)[o4]     = make_float4(a[0], a[1], a[2], a[3]);
            ((float4*)outbuf)[o4 + 1] = make_float4(a[4], a[5], a[6], a[7]);
        }
        // fused stage-2 stats: relu(a + b1) per channel
        #pragma unroll
        for (int j = 0; j < 8; ++j) {
            float vv = valid ? fmaxf(a[j] + bias[c + j], 0.f) : 0.f;
            sh1[tid][j] = vv;
            sh2[tid][j] = vv * vv;
        }
        __syncthreads();
        if (tid < 128) {
            int lane16 = tid >> 3;
            int j = tid & 7;
            float s = 0.f, s2 = 0.f;
            #pragma unroll
            for (int g = 0; g < 16; ++g) {
                s  += sh1[g * 16 + lane16][j];
                s2 += sh2[g * 16 + lane16][j];
            }
            partials[(size_t)blockIdx.x * 256 + tid]       = s;
            partials[(size_t)blockIdx.x * 256 + 128 + tid] = s2;
        }
    }
}

extern "C" void kernel_launch(void* const* d_in, const int* in_sizes, int n_in,
                              void* d_out, int out_size, void* d_ws, size_t ws_size,
                              hipStream_t stream) {
    const float* x      = (const float*)d_in[0];
    const int*   eidx   = (const int*)d_in[1];
    const float* W1     = (const float*)d_in[2];
    const float* b1     = (const float*)d_in[3];
    const float* W2     = (const float*)d_in[4];
    const float* b2     = (const float*)d_in[5];
    const float* gamma1 = (const float*)d_in[6];
    const float* beta1  = (const float*)d_in[7];
    const float* gamma2 = (const float*)d_in[8];
    const float* beta2  = (const float*)d_in[9];
    float* out = (float*)d_out;

    const int N = in_sizes[0] / CH;
    const int E = in_sizes[1] / 2;
    const int* src = eidx;
    const int* dst = eidx + E;

    const int NAGG = (N + 15) / 16;

    char* ws = (char*)d_ws;
    size_t off = 0;
    auto carve = [&](size_t bytes) { char* p = ws + off; off = (off + bytes + 1023) & ~(size_t)1023; return p; };
    int*    cnt      = (int*)carve((size_t)(N + 1) * 4);  // cnt[N] = scan cursor
    float*  dinv     = (float*)carve((size_t)N * 4);
    int*    offs     = (int*)carve((size_t)N * 4);
    int*    slot     = (int*)carve((size_t)E * 4);
    float*  small    = (float*)carve(8 * CH * 4);
    float*  partials = (float*)carve((size_t)NAGG * 256 * 4);  // max(stats 256, agg 6250)
    float*  partials2= (float*)carve((size_t)FOLD_BLOCKS * 256 * 4);
    int2*   csr      = (int2*)carve((size_t)E * 8);
    __bf16* W1b      = (__bf16*)carve((size_t)CH * CH * 2);
    __bf16* W2b      = (__bf16*)carve((size_t)CH * CH * 2);
    __bf16* h_bf     = (__bf16*)carve((size_t)N * CH * 2);
    float*  agg_buf  = (float*)carve((size_t)N * CH * 4);
    float* scale1 = small + 4 * CH;
    float* shift1 = small + 5 * CH;
    float* scale2 = small + 6 * CH;
    float* shift2 = small + 7 * CH;
    (void)ws_size; (void)n_in; (void)out_size;

    int* cursor = cnt + N;
    hipMemsetAsync(cnt, 0, (size_t)(N + 1) * 4, stream);

    const int NB_COUNT = (E + 255) / 256;
    const int NB_STATS = STATS_BLOCKS;
    const int NB_WPREP = (2 * CH * CH + 255) / 256;
    const int NB_SCAN  = (N + 1023) / 1024;
    const int NB_DINV  = (N + 1023) / 1024;
    const int NB_FILL  = (E + 255) / 256;
    const int NB_GEMM  = (N + GROWS - 1) / GROWS;

    // K1: count + stats1(x) + weight bf16 prep
    k1_kernel<<<NB_COUNT + NB_STATS + NB_WPREP, 256, 0, stream>>>(
        dst, cnt, slot, E, x, partials, N * 32, W1, W2, W1b, W2b,
        NB_COUNT, NB_STATS);

    // K2: scan(atomic base) + dinv + reduce1/bnparam1 (R=256 now)
    k2_kernel<<<NB_SCAN + NB_DINV + 16, 256, 0, stream>>>(
        cnt, offs, cursor, dinv, N, partials, gamma1, beta1,
        scale1, shift1, STATS_BLOCKS, NB_SCAN, NB_DINV);

    // fill CSR (standalone, max occupancy for the random scatter)
    fill_kernel<<<NB_FILL, 256, 0, stream>>>(src, dst, slot, offs, dinv, csr, E);

    // gemm1 (standalone MFMA)
    gemm_kernel<<<NB_GEMM, 256, 0, stream>>>(x, nullptr, 0, scale1, shift1,
                                             W1b, h_bf, N, 0);

    // agg1 + fused stats2 partials
    agg_kernel<<<NAGG, 256, 0, stream>>>(h_bf, csr, offs, cnt, dinv,
                                         b1, nullptr, agg_buf, partials, N, 0);

    // fold 6250 partial rows -> 256 (coalesced, full BW), then reduce2+bn2
    fold_kernel<<<FOLD_BLOCKS, 256, 0, stream>>>(partials, partials2, NAGG);
    reducebn_kernel<<<16, 256, 0, stream>>>(partials2, FOLD_BLOCKS, gamma2, beta2,
                                            scale2, shift2, N);

    // gemm2 (nontemporal A read: last use of agg_buf)
    gemm_kernel<<<NB_GEMM, 256, 0, stream>>>(agg_buf, b1, 1, scale2, shift2,
                                             W2b, h_bf, N, 1);

    // agg2: final relu + bias + residual
    agg_kernel<<<NAGG, 256, 0, stream>>>(h_bf, csr, offs, cnt, dinv,
                                         b2, x, out, nullptr, N, 1);
}

// Round 4
// 388.655 us; speedup vs baseline: 1.1900x; 1.0398x over previous
//
#include <hip/hip_runtime.h>
#include <hip/hip_bf16.h>
#include <cstddef>

#define CH 128
#define BN_EPS 1e-5f
#define STATS_BLOCKS 2048
#define FOLD_BLOCKS 256

typedef __bf16 bf16x8 __attribute__((ext_vector_type(8)));
typedef __bf16 bf16x4 __attribute__((ext_vector_type(4)));
typedef float  f32x4  __attribute__((ext_vector_type(4)));

__device__ inline float bf2f(__bf16 b) { return (float)b; }

__device__ inline f32x4 nt_load4(const float* p) {
    return __builtin_nontemporal_load((const f32x4*)p);
}
__device__ inline void nt_store4(float* p, f32x4 v) {
    __builtin_nontemporal_store(v, (f32x4*)p);
}

// ---------------------------------------------------------------------------
// R10: (a) undo R9's stats1 occupancy regression (256 blocks = 1 block/CU =
// ~2TB/s; back to 2048 via fold1-in-k2, reducebn1 moved to fill tail).
// (b) count/fill 4 edges/thread for 4 independent latency chains in flight.
// (c) BN2-commute: BN2(r)@W2^T = r@(scale2*W2)^T + shift2^T W2, so agg1
// writes relu(a+b1) as bf16 (25.6MB not 51.2MB f32), gemm2 reads bf16 with
// prescaled W2' and folded bias'. W2'/bias' prep fused into reducebn2.
// ---------------------------------------------------------------------------

// ---- K1: count (4 edges/thread) + stats1 over x + wprep W1 -> bf16 ---------
__global__ __launch_bounds__(256) void k1_kernel(
    const int* __restrict__ dst, int* __restrict__ cnt, int* __restrict__ slot, int E,
    const float* __restrict__ x, float* __restrict__ partials, int total4,
    const float* __restrict__ W1, __bf16* __restrict__ W1b,
    int NB_COUNT4, int NB_STATS) {
    int b = blockIdx.x;
    if (b < NB_COUNT4) {
        int base = b * 1024 + threadIdx.x;
        #pragma unroll
        for (int j = 0; j < 4; ++j) {
            int e = base + j * 256;
            if (e < E) slot[e] = atomicAdd(&cnt[dst[e]], 1);
        }
    } else if (b < NB_COUNT4 + NB_STATS) {
        // per-channel sum & sumsq -> per-block partial row (sums||sumsq)
        int sbid = b - NB_COUNT4;
        int l = threadIdx.x & 31;
        int g = threadIdx.x >> 5;
        float4 s  = make_float4(0.f, 0.f, 0.f, 0.f);
        float4 s2 = make_float4(0.f, 0.f, 0.f, 0.f);
        int gid = sbid * 256 + threadIdx.x;
        int gs = NB_STATS * 256;
        const float4* in4 = (const float4*)x;

        auto accum = [&](float4 v) {
            s.x += v.x; s.y += v.y; s.z += v.z; s.w += v.w;
            s2.x += v.x * v.x; s2.y += v.y * v.y; s2.z += v.z * v.z; s2.w += v.w * v.w;
        };

        int i = gid;
        for (; i + 3 * gs < total4; i += 4 * gs) {
            float4 v0 = in4[i];
            float4 v1 = in4[i + gs];
            float4 v2 = in4[i + 2 * gs];
            float4 v3 = in4[i + 3 * gs];
            accum(v0); accum(v1); accum(v2); accum(v3);
        }
        for (; i < total4; i += gs) accum(in4[i]);

        __shared__ float4 ls[8][32], ls2[8][32];
        ls[g][l] = s; ls2[g][l] = s2;
        __syncthreads();
        if (g == 0) {
            #pragma unroll
            for (int k = 1; k < 8; ++k) {
                float4 a = ls[k][l], bb = ls2[k][l];
                s.x += a.x; s.y += a.y; s.z += a.z; s.w += a.w;
                s2.x += bb.x; s2.y += bb.y; s2.z += bb.z; s2.w += bb.w;
            }
            ((float4*)partials)[sbid * 64 + l]      = s;
            ((float4*)partials)[sbid * 64 + 32 + l] = s2;
        }
    } else {
        int i = (b - NB_COUNT4 - NB_STATS) * 256 + threadIdx.x;
        if (i < CH * CH) W1b[i] = (__bf16)W1[i];
    }
}

// ---- reduce partial rows + BN params (8 channels per block) ----------------
__device__ inline void reducebn_body(
    int blk, const float* __restrict__ partials, int R,
    const float* __restrict__ gamma, const float* __restrict__ beta,
    float* __restrict__ scale, float* __restrict__ shift, float inv_n) {
    __shared__ float l1[256], l2[256];
    int t = threadIdx.x;
    int cl = t & 7;
    int r0 = t >> 3;
    int c = blk * 8 + cl;
    float a1 = 0.f, a2 = 0.f;
    for (int r = r0; r < R; r += 32) {
        a1 += partials[(size_t)r * 256 + c];
        a2 += partials[(size_t)r * 256 + 128 + c];
    }
    l1[t] = a1; l2[t] = a2;
    __syncthreads();
    #pragma unroll
    for (int off = 16; off >= 1; off >>= 1) {
        if (r0 < off) {
            l1[t] += l1[t + off * 8];
            l2[t] += l2[t + off * 8];
        }
        __syncthreads();
    }
    if (t < 8) {
        float mean = l1[t] * inv_n;
        float var  = l2[t] * inv_n - mean * mean;  // biased
        float sc = gamma[c] * rsqrtf(var + BN_EPS);
        scale[c] = sc;
        shift[c] = beta[c] - mean * sc;
    }
}

// ---- K2: atomic-base scan + dinv + fold1 -----------------------------------
__global__ __launch_bounds__(256) void k2_kernel(
    const int* __restrict__ cnt, int* __restrict__ offs, int* __restrict__ cursor,
    float* __restrict__ dinv, int n,
    const float* __restrict__ partials, float* __restrict__ partials2,
    int NB_SCAN, int NB_DINV) {
    int b = blockIdx.x;
    int t = threadIdx.x;
    if (b < NB_SCAN) {
        __shared__ int sd[256];
        __shared__ int sbase;
        int base = b * 1024 + t * 4;
        int v[4];
        #pragma unroll
        for (int j = 0; j < 4; ++j) v[j] = (base + j < n) ? cnt[base + j] : 0;
        int s = v[0] + v[1] + v[2] + v[3];
        sd[t] = s;
        __syncthreads();
        for (int off = 1; off < 256; off <<= 1) {
            int xv = (t >= off) ? sd[t - off] : 0;
            __syncthreads();
            sd[t] += xv;
            __syncthreads();
        }
        if (t == 255) sbase = atomicAdd(cursor, sd[255]);
        __syncthreads();
        int run = sbase + sd[t] - s;
        #pragma unroll
        for (int j = 0; j < 4; ++j) {
            if (base + j < n) offs[base + j] = run;
            run += v[j];
        }
    } else if (b < NB_SCAN + NB_DINV) {
        int ib = (b - NB_SCAN) * 1024 + t * 4;
        #pragma unroll
        for (int j = 0; j < 4; ++j) {
            int i = ib + j;
            if (i < n) dinv[i] = rsqrtf((float)cnt[i] + 1.0f);  // +1 self loop
        }
    } else {
        // fold1: STATS_BLOCKS partial rows -> FOLD_BLOCKS rows
        int fb = b - NB_SCAN - NB_DINV;
        float acc = 0.f;
        for (int r = fb; r < STATS_BLOCKS; r += FOLD_BLOCKS)
            acc += partials[(size_t)r * 256 + t];
        partials2[(size_t)fb * 256 + t] = acc;
    }
}

// ---- fill CSR (4 edges/thread) + reducebn1 tail blocks ---------------------
__global__ __launch_bounds__(256) void fill_kernel(
    const int* __restrict__ src, const int* __restrict__ dst,
    const int* __restrict__ slot, const int* __restrict__ offs,
    const float* __restrict__ dinv, int2* __restrict__ csr, int E,
    const float* __restrict__ partials2,
    const float* __restrict__ gamma1, const float* __restrict__ beta1,
    float* __restrict__ scale1, float* __restrict__ shift1, int n,
    int NB_FILL4) {
    int b = blockIdx.x;
    if (b < NB_FILL4) {
        int base = b * 1024 + threadIdx.x;
        #pragma unroll
        for (int j = 0; j < 4; ++j) {
            int e = base + j * 256;
            if (e < E) {
                int s = src[e], d = dst[e];
                int p = offs[d] + slot[e];
                float nrm = dinv[s] * dinv[d];
                csr[p] = make_int2(s, __float_as_int(nrm));
            }
        }
    } else {
        reducebn_body(b - NB_FILL4, partials2, FOLD_BLOCKS, gamma1, beta1,
                      scale1, shift1, 1.0f / (float)n);
    }
}

// ---- fold: R partial rows -> FOLD_BLOCKS rows ------------------------------
__global__ __launch_bounds__(256) void fold_kernel(
    const float* __restrict__ partials, float* __restrict__ out, int R) {
    int t = threadIdx.x;
    float acc = 0.f;
    for (int r = blockIdx.x; r < R; r += FOLD_BLOCKS)
        acc += __builtin_nontemporal_load(&partials[(size_t)r * 256 + t]);
    out[(size_t)blockIdx.x * 256 + t] = acc;
}

// ---- reducebn2 + W2' prep + bias' partials (16 blocks, 8 channels each) ----
__global__ __launch_bounds__(256) void rbn2w2_kernel(
    const float* __restrict__ partials2,
    const float* __restrict__ gamma, const float* __restrict__ beta,
    const float* __restrict__ W2, __bf16* __restrict__ W2b,
    float* __restrict__ bias2p, int n) {
    __shared__ float l1[256], l2[256];
    __shared__ float ssc[8], ssh[8];
    int t = threadIdx.x;
    int blk = blockIdx.x;
    int cl = t & 7;
    int r0 = t >> 3;
    int c = blk * 8 + cl;
    float a1 = 0.f, a2 = 0.f;
    for (int r = r0; r < FOLD_BLOCKS; r += 32) {
        a1 += partials2[(size_t)r * 256 + c];
        a2 += partials2[(size_t)r * 256 + 128 + c];
    }
    l1[t] = a1; l2[t] = a2;
    __syncthreads();
    #pragma unroll
    for (int off = 16; off >= 1; off >>= 1) {
        if (r0 < off) {
            l1[t] += l1[t + off * 8];
            l2[t] += l2[t + off * 8];
        }
        __syncthreads();
    }
    if (t < 8) {
        int cc = blk * 8 + t;
        float inv_n = 1.0f / (float)n;
        float mean = l1[t] * inv_n;
        float var  = l2[t] * inv_n - mean * mean;
        float sc = gamma[cc] * rsqrtf(var + BN_EPS);
        float sh = beta[cc] - mean * sc;
        ssc[t] = sc;
        ssh[t] = sh;
    }
    __syncthreads();
    // W2' columns blk*8 .. blk*8+7 : W2'[j][k] = W2[j][k] * scale2[k]
    for (int idx = t; idx < 128 * 8; idx += 256) {
        int j = idx >> 3, kk = idx & 7;
        int k = blk * 8 + kk;
        W2b[j * CH + k] = (__bf16)(W2[j * CH + k] * ssc[kk]);
    }
    // bias' partial: bias2p[j] += sum_kk shift2[k] * W2[j][k]
    if (t < CH) {
        float acc = 0.f;
        #pragma unroll
        for (int kk = 0; kk < 8; ++kk)
            acc += ssh[kk] * W2[t * CH + blk * 8 + kk];
        atomicAdd(&bias2p[t], acc);
    }
}

// ---- MFMA GEMM 1: f32 A with BN1 transform ---------------------------------
#define GROWS 64
#define LDA 136

__global__ __launch_bounds__(256) void gemm_kernel(
    const float* __restrict__ A,
    const float* __restrict__ scale, const float* __restrict__ shift,
    const __bf16* __restrict__ Wb, __bf16* __restrict__ Hout, int n) {
    __shared__ __bf16 As[GROWS][LDA];
    int tid = threadIdx.x;
    int row0 = blockIdx.x * GROWS;

    #pragma unroll
    for (int p = 0; p < 8; ++p) {
        int idx = p * 256 + tid;
        int r = idx >> 5;
        int f4 = idx & 31;
        int c4 = f4 * 4;
        int row = row0 + r;
        f32x4 v = {0.f, 0.f, 0.f, 0.f};
        if (row < n) v = *((const f32x4*)A + ((size_t)row * 32 + f4));
        __bf16 u[4];
        #pragma unroll
        for (int j = 0; j < 4; ++j) {
            int ch = c4 + j;
            u[j] = (__bf16)(v[j] * scale[ch] + shift[ch]);
        }
        *(bf16x4*)&As[r][c4] = *(bf16x4*)u;
    }
    __syncthreads();

    int wv = tid >> 6;
    int lane = tid & 63;
    int m = lane & 15;
    int q = lane >> 4;
    int arow = wv * 16 + m;
    f32x4 acc[8] = {};
    #pragma unroll
    for (int kc = 0; kc < CH; kc += 32) {
        bf16x8 af = *(const bf16x8*)&As[arow][kc + q * 8];
        #pragma unroll
        for (int t = 0; t < 8; ++t) {
            bf16x8 bf = *(const bf16x8*)&Wb[(size_t)(t * 16 + m) * CH + kc + q * 8];
            acc[t] = __builtin_amdgcn_mfma_f32_16x16x32_bf16(af, bf, acc[t], 0, 0, 0);
        }
    }

    #pragma unroll
    for (int t = 0; t < 8; ++t) {
        #pragma unroll
        for (int r = 0; r < 4; ++r) {
            int row = row0 + wv * 16 + q * 4 + r;
            if (row < n) Hout[(size_t)row * CH + t * 16 + m] = (__bf16)acc[t][r];
        }
    }
}

// ---- MFMA GEMM 2: bf16 A (raw relu), prescaled W2', folded bias' -----------
__global__ __launch_bounds__(256) void gemm_bf_kernel(
    const __bf16* __restrict__ A, const __bf16* __restrict__ Wb,
    const float* __restrict__ bias2p, __bf16* __restrict__ Hout, int n) {
    __shared__ __bf16 As[GROWS][LDA];
    int tid = threadIdx.x;
    int row0 = blockIdx.x * GROWS;

    #pragma unroll
    for (int p = 0; p < 4; ++p) {
        int idx = p * 256 + tid;
        int r = idx >> 4;          // 64 rows, 16 slots of bf16x8
        int f8 = idx & 15;
        int c8 = f8 * 8;
        int row = row0 + r;
        bf16x8 v = {};
        if (row < n) v = *(const bf16x8*)&A[(size_t)row * CH + c8];
        *(bf16x8*)&As[r][c8] = v;
    }
    __syncthreads();

    int wv = tid >> 6;
    int lane = tid & 63;
    int m = lane & 15;
    int q = lane >> 4;
    int arow = wv * 16 + m;
    f32x4 acc[8] = {};
    #pragma unroll
    for (int kc = 0; kc < CH; kc += 32) {
        bf16x8 af = *(const bf16x8*)&As[arow][kc + q * 8];
        #pragma unroll
        for (int t = 0; t < 8; ++t) {
            bf16x8 bf = *(const bf16x8*)&Wb[(size_t)(t * 16 + m) * CH + kc + q * 8];
            acc[t] = __builtin_amdgcn_mfma_f32_16x16x32_bf16(af, bf, acc[t], 0, 0, 0);
        }
    }

    #pragma unroll
    for (int t = 0; t < 8; ++t) {
        float bc = bias2p[t * 16 + m];
        #pragma unroll
        for (int r = 0; r < 4; ++r) {
            int row = row0 + wv * 16 + q * 4 + r;
            if (row < n) Hout[(size_t)row * CH + t * 16 + m] = (__bf16)(acc[t][r] + bc);
        }
    }
}

// ---------------------------------------------------------------------------
// Gather core: a[8] = dinv^2 * h[node] + sum_e norm_e * h[src_e]
// ---------------------------------------------------------------------------
__device__ inline void agg_core(
    const __bf16* __restrict__ h, const int2* __restrict__ csr,
    const int* __restrict__ offs, const int* __restrict__ cnt,
    const float* __restrict__ dinv, int node, int c, bool valid, float a[8]) {
    int e = 0, end = 0;
    if (valid) {
        float di = dinv[node];
        float w0 = di * di;
        bf16x8 hv = *(const bf16x8*)&h[(size_t)node * CH + c];
        #pragma unroll
        for (int j = 0; j < 8; ++j) a[j] = bf2f(hv[j]) * w0;
        e = offs[node];
        end = e + cnt[node];
    }
    for (; e + 4 <= end; e += 4) {
        int2 p0 = csr[e], p1 = csr[e + 1], p2 = csr[e + 2], p3 = csr[e + 3];
        bf16x8 v0 = *(const bf16x8*)&h[(size_t)p0.x * CH + c];
        bf16x8 v1 = *(const bf16x8*)&h[(size_t)p1.x * CH + c];
        bf16x8 v2 = *(const bf16x8*)&h[(size_t)p2.x * CH + c];
        bf16x8 v3 = *(const bf16x8*)&h[(size_t)p3.x * CH + c];
        float n0 = __int_as_float(p0.y), n1 = __int_as_float(p1.y);
        float n2 = __int_as_float(p2.y), n3 = __int_as_float(p3.y);
        #pragma unroll
        for (int j = 0; j < 8; ++j) {
            a[j] += bf2f(v0[j]) * n0;
            a[j] += bf2f(v1[j]) * n1;
            a[j] += bf2f(v2[j]) * n2;
            a[j] += bf2f(v3[j]) * n3;
        }
    }
    for (; e < end; ++e) {
        int2 p0 = csr[e];
        float n0 = __int_as_float(p0.y);
        bf16x8 v0 = *(const bf16x8*)&h[(size_t)p0.x * CH + c];
        #pragma unroll
        for (int j = 0; j < 8; ++j) a[j] += bf2f(v0[j]) * n0;
    }
}

// agg1: relu(a + b1) -> bf16 h2raw + fused stage-2 stats partials
__global__ __launch_bounds__(256) void agg1_kernel(
    const __bf16* __restrict__ h, const int2* __restrict__ csr,
    const int* __restrict__ offs, const int* __restrict__ cnt,
    const float* __restrict__ dinv, const float* __restrict__ b1,
    __bf16* __restrict__ h2raw, float* __restrict__ partials, int n) {
    __shared__ float sh1[256][8];
    __shared__ float sh2[256][8];
    int tid = threadIdx.x;
    int node = blockIdx.x * 16 + (tid >> 4);
    int c = (tid & 15) * 8;
    bool valid = node < n;
    float a[8] = {0.f, 0.f, 0.f, 0.f, 0.f, 0.f, 0.f, 0.f};
    agg_core(h, csr, offs, cnt, dinv, node, c, valid, a);

    float r[8];
    #pragma unroll
    for (int j = 0; j < 8; ++j) r[j] = valid ? fmaxf(a[j] + b1[c + j], 0.f) : 0.f;

    if (valid) {
        __bf16 u[8];
        #pragma unroll
        for (int j = 0; j < 8; ++j) u[j] = (__bf16)r[j];
        *(bf16x8*)&h2raw[(size_t)node * CH + c] = *(bf16x8*)u;
    }

    #pragma unroll
    for (int j = 0; j < 8; ++j) {
        sh1[tid][j] = r[j];
        sh2[tid][j] = r[j] * r[j];
    }
    __syncthreads();
    if (tid < 128) {
        int lane16 = tid >> 3;
        int j = tid & 7;
        float s = 0.f, s2 = 0.f;
        #pragma unroll
        for (int g = 0; g < 16; ++g) {
            s  += sh1[g * 16 + lane16][j];
            s2 += sh2[g * 16 + lane16][j];
        }
        partials[(size_t)blockIdx.x * 256 + tid]       = s;
        partials[(size_t)blockIdx.x * 256 + 128 + tid] = s2;
    }
}

// agg2: final relu(a + b2) + residual x, nt store to out
__global__ __launch_bounds__(256) void agg2_kernel(
    const __bf16* __restrict__ h, const int2* __restrict__ csr,
    const int* __restrict__ offs, const int* __restrict__ cnt,
    const float* __restrict__ dinv, const float* __restrict__ b2,
    const float* __restrict__ x, float* __restrict__ out, int n) {
    int tid = threadIdx.x;
    int node = blockIdx.x * 16 + (tid >> 4);
    int c = (tid & 15) * 8;
    bool valid = node < n;
    float a[8] = {0.f, 0.f, 0.f, 0.f, 0.f, 0.f, 0.f, 0.f};
    agg_core(h, csr, offs, cnt, dinv, node, c, valid, a);
    if (!valid) return;

    size_t o4 = (size_t)node * 32 + (c >> 2);
    f32x4 xb0 = nt_load4(&x[o4 * 4]);
    f32x4 xb1 = nt_load4(&x[o4 * 4 + 4]);
    f32x4 bb0 = *(const f32x4*)&b2[c];
    f32x4 bb1 = *(const f32x4*)&b2[c + 4];
    f32x4 o0, o1;
    o0[0] = fmaxf(a[0] + bb0[0], 0.f) + xb0[0];
    o0[1] = fmaxf(a[1] + bb0[1], 0.f) + xb0[1];
    o0[2] = fmaxf(a[2] + bb0[2], 0.f) + xb0[2];
    o0[3] = fmaxf(a[3] + bb0[3], 0.f) + xb0[3];
    o1[0] = fmaxf(a[4] + bb1[0], 0.f) + xb1[0];
    o1[1] = fmaxf(a[5] + bb1[1], 0.f) + xb1[1];
    o1[2] = fmaxf(a[6] + bb1[2], 0.f) + xb1[2];
    o1[3] = fmaxf(a[7] + bb1[3], 0.f) + xb1[3];
    nt_store4(&out[o4 * 4], o0);
    nt_store4(&out[o4 * 4 + 4], o1);
}

extern "C" void kernel_launch(void* const* d_in, const int* in_sizes, int n_in,
                              void* d_out, int out_size, void* d_ws, size_t ws_size,
                              hipStream_t stream) {
    const float* x      = (const float*)d_in[0];
    const int*   eidx   = (const int*)d_in[1];
    const float* W1     = (const float*)d_in[2];
    const float* b1     = (const float*)d_in[3];
    const float* W2     = (const float*)d_in[4];
    const float* b2     = (const float*)d_in[5];
    const float* gamma1 = (const float*)d_in[6];
    const float* beta1  = (const float*)d_in[7];
    const float* gamma2 = (const float*)d_in[8];
    const float* beta2  = (const float*)d_in[9];
    float* out = (float*)d_out;

    const int N = in_sizes[0] / CH;
    const int E = in_sizes[1] / 2;
    const int* src = eidx;
    const int* dst = eidx + E;

    const int NAGG = (N + 15) / 16;

    char* ws = (char*)d_ws;
    size_t off = 0;
    auto carve = [&](size_t bytes) { char* p = ws + off; off = (off + bytes + 1023) & ~(size_t)1023; return p; };
    int*    cnt      = (int*)carve((size_t)(N + 1) * 4);  // cnt[N] = scan cursor
    float*  bias2p   = (float*)carve(CH * 4);             // zeroed with cnt (adjacent)
    float*  dinv     = (float*)carve((size_t)N * 4);
    int*    offs     = (int*)carve((size_t)N * 4);
    int*    slot     = (int*)carve((size_t)E * 4);
    float*  small    = (float*)carve(8 * CH * 4);
    float*  partials = (float*)carve((size_t)NAGG * 256 * 4);  // max(STATS_BLOCKS, NAGG) rows
    float*  partials2= (float*)carve((size_t)FOLD_BLOCKS * 256 * 4);
    int2*   csr      = (int2*)carve((size_t)E * 8);
    __bf16* W1b      = (__bf16*)carve((size_t)CH * CH * 2);
    __bf16* W2b      = (__bf16*)carve((size_t)CH * CH * 2);  // holds W2' (prescaled)
    __bf16* h_bf     = (__bf16*)carve((size_t)N * CH * 2);
    __bf16* h2raw    = (__bf16*)carve((size_t)N * CH * 2);   // relu(agg1+b1), bf16
    float* scale1 = small + 4 * CH;
    float* shift1 = small + 5 * CH;
    (void)ws_size; (void)n_in; (void)out_size;

    int* cursor = cnt + N;
    // one memset covers cnt+cursor and bias2p (adjacent carves)
    size_t zbytes = (size_t)((char*)bias2p - (char*)cnt) + CH * 4;
    hipMemsetAsync(cnt, 0, zbytes, stream);

    const int NB_COUNT4 = (E + 1023) / 1024;
    const int NB_STATS  = STATS_BLOCKS;
    const int NB_WPREP  = (CH * CH + 255) / 256;
    const int NB_SCAN   = (N + 1023) / 1024;
    const int NB_DINV   = (N + 1023) / 1024;
    const int NB_FILL4  = (E + 1023) / 1024;
    const int NB_GEMM   = (N + GROWS - 1) / GROWS;

    // K1: count(4/thread) + stats1(x)@2048 + W1 bf16 prep
    k1_kernel<<<NB_COUNT4 + NB_STATS + NB_WPREP, 256, 0, stream>>>(
        dst, cnt, slot, E, x, partials, N * 32, W1, W1b, NB_COUNT4, NB_STATS);

    // K2: scan(atomic base) + dinv + fold1 (2048 -> 256 rows)
    k2_kernel<<<NB_SCAN + NB_DINV + FOLD_BLOCKS, 256, 0, stream>>>(
        cnt, offs, cursor, dinv, N, partials, partials2, NB_SCAN, NB_DINV);

    // fill CSR (4/thread) + reducebn1 tail (16 blocks)
    fill_kernel<<<NB_FILL4 + 16, 256, 0, stream>>>(
        src, dst, slot, offs, dinv, csr, E,
        partials2, gamma1, beta1, scale1, shift1, N, NB_FILL4);

    // gemm1: h = BN1(x) @ W1^T  (bf16 out)
    gemm_kernel<<<NB_GEMM, 256, 0, stream>>>(x, scale1, shift1, W1b, h_bf, N);

    // agg1: relu(A-hat h + b1) -> h2raw bf16 + stats2 partials
    agg1_kernel<<<NAGG, 256, 0, stream>>>(h_bf, csr, offs, cnt, dinv,
                                          b1, h2raw, partials, N);

    // fold2: NAGG partial rows -> 256
    fold_kernel<<<FOLD_BLOCKS, 256, 0, stream>>>(partials, partials2, NAGG);

    // reducebn2 + W2' prep + bias' accumulation
    rbn2w2_kernel<<<16, 256, 0, stream>>>(partials2, gamma2, beta2,
                                          W2, W2b, bias2p, N);

    // gemm2: h2 = h2raw @ W2'^T + bias'  (bf16 out)
    gemm_bf_kernel<<<NB_GEMM, 256, 0, stream>>>(h2raw, W2b, bias2p, h_bf, N);

    // agg2: out = relu(A-hat h2 + b2) + x
    agg2_kernel<<<NAGG, 256, 0, stream>>>(h_bf, csr, offs, cnt, dinv,
                                          b2, x, out, N);
}